// Round 1
// baseline (2119.853 us; speedup 1.0000x reference)
//
#include <hip/hip_runtime.h>

#define NN 4
#define C  64
#define CF 72
#define HH 256
#define WW 256
#define HW (HH*WW)
#define EPSV 1e-5f

__device__ __forceinline__ float leakyf(float x){ return x >= 0.f ? x : 0.01f*x; }

// ---------------- weight pre-transpose: [cout][cin][9] -> [cin][tap][cout] ----------------
__global__ void prep_weights(const float* __restrict__ w1, const float* __restrict__ wf,
                             const float* __restrict__ w2, const float* __restrict__ wr,
                             float* __restrict__ wT1, float* __restrict__ wTf,
                             float* __restrict__ wT2, float* __restrict__ wrT){
  int i = blockIdx.x*256 + threadIdx.x;
  if (i < C*C*9){
    int cout = i/(C*9); int rem = i%(C*9); int cin = rem/9; int tap = rem%9;
    int dst = cin*(9*C) + tap*C + cout;
    wT1[dst] = w1[i];
    wT2[dst] = w2[i];
  }
  if (i < CF*C*9){
    int cout = i/(C*9); int rem = i%(C*9); int cin = rem/9; int tap = rem%9;
    wTf[cin*(9*CF) + tap*CF + cout] = wf[i];
  }
  if (i < C*C){
    int cout = i/C; int cin = i%C;
    wrT[cin*C + cout] = wr[i];
  }
}

// ---------------- shared conv core: block = one (n,h) row, thread = one pixel ----------------
template<int COUT, bool REFLECT>
__device__ __forceinline__ void conv_core(const float* __restrict__ in_n,
                                          const float* __restrict__ wT,
                                          int h, int t, float* acc,
                                          float (*ls)[WW+2], float* lw){
  for (int ci = 0; ci < C; ++ci){
    __syncthreads();
    #pragma unroll
    for (int r = 0; r < 3; ++r){
      int hh = h + r - 1;
      bool valid = true;
      if (REFLECT) hh = (hh < 0) ? 1 : ((hh >= HH) ? (HH-2) : hh);
      else { valid = (hh >= 0) && (hh < HH); if (!valid) hh = 0; }
      const float* row = in_n + ci*HW + hh*WW;
      ls[r][t+1] = valid ? row[t] : 0.f;
      if (t == 0)   ls[r][0]     = REFLECT ? row[1]    : 0.f;
      if (t == 255) ls[r][WW+1]  = REFLECT ? row[WW-2] : 0.f;
    }
    for (int j = t; j < 9*COUT; j += 256) lw[j] = wT[ci*9*COUT + j];
    __syncthreads();
    #pragma unroll
    for (int k = 0; k < 9; ++k){
      float v = ls[k/3][t + (k%3)];
      const float4* w4 = reinterpret_cast<const float4*>(lw + k*COUT);
      #pragma unroll
      for (int q = 0; q < COUT/4; ++q){
        float4 wv = w4[q];
        acc[4*q+0] = fmaf(v, wv.x, acc[4*q+0]);
        acc[4*q+1] = fmaf(v, wv.y, acc[4*q+1]);
        acc[4*q+2] = fmaf(v, wv.z, acc[4*q+2]);
        acc[4*q+3] = fmaf(v, wv.w, acc[4*q+3]);
      }
    }
  }
}

// ---------------- conv1: y1 = conv3x3(x, zero pad) + b1 ----------------
__global__ __launch_bounds__(256) void conv1_kernel(const float* __restrict__ x,
                                                    const float* __restrict__ wT1,
                                                    const float* __restrict__ b1,
                                                    float* __restrict__ y1){
  __shared__ float ls[3][WW+2];
  __shared__ __align__(16) float lw[9*C];
  int t = threadIdx.x;
  int nh = blockIdx.x, n = nh / HH, h = nh % HH;
  float acc[C];
  #pragma unroll
  for (int co = 0; co < C; ++co) acc[co] = b1[co];
  conv_core<C, false>(x + (size_t)n*C*HW, wT1, h, t, acc, ls, lw);
  float* yo = y1 + (size_t)n*C*HW + h*WW + t;
  #pragma unroll
  for (int co = 0; co < C; ++co) yo[co*HW] = acc[co];
}

// ---------------- pass A: sig = conv3x3(reflectpad(y1), wf); accumulate per-channel sum/sumsq ----------------
__global__ __launch_bounds__(256) void passA_kernel(const float* __restrict__ y1,
                                                    const float* __restrict__ wTf,
                                                    float* __restrict__ sigsum,
                                                    float* __restrict__ sigsumsq){
  __shared__ float ls[3][WW+2];
  __shared__ __align__(16) float lw[9*CF];
  __shared__ float part[CF][2][4];
  int t = threadIdx.x, lane = t & 63, wv = t >> 6;
  int nh = blockIdx.x, n = nh / HH, h = nh % HH;
  float acc[CF];
  #pragma unroll
  for (int c = 0; c < CF; ++c) acc[c] = 0.f;
  conv_core<CF, true>(y1 + (size_t)n*C*HW, wTf, h, t, acc, ls, lw);
  #pragma unroll
  for (int c = 0; c < CF; ++c){
    float s = acc[c], q = acc[c]*acc[c];
    #pragma unroll
    for (int d = 32; d; d >>= 1){ s += __shfl_xor(s, d); q += __shfl_xor(q, d); }
    if (lane == 0){ part[c][0][wv] = s; part[c][1][wv] = q; }
  }
  __syncthreads();
  if (t < CF*2){
    int c = t >> 1, which = t & 1;
    float s = part[c][which][0] + part[c][which][1] + part[c][which][2] + part[c][which][3];
    atomicAdd(which ? &sigsumsq[c] : &sigsum[c], s);
  }
}

// ---------------- BN stat finalize ----------------
__global__ void bnstats_kernel(const float* __restrict__ sigsum, const float* __restrict__ sigsumsq,
                               const float* __restrict__ gamma, const float* __restrict__ beta,
                               float* __restrict__ bnscale, float* __restrict__ bnshift){
  int c = threadIdx.x;
  if (c < CF){
    const float M = (float)((size_t)NN*HW);
    float mu  = sigsum[c] / M;
    float var = sigsumsq[c] / M - mu*mu;
    float sc  = gamma[c] * rsqrtf(var + EPSV);
    bnscale[c] = sc;
    bnshift[c] = beta[c] - mu*sc;
  }
}

// ---------------- pass B: recompute sig, BN+softmax, spatially-varying filter; hin partial stats ----------------
__global__ __launch_bounds__(256) void passB_kernel(const float* __restrict__ y1,
                                                    const float* __restrict__ wTf,
                                                    const float* __restrict__ bnscale,
                                                    const float* __restrict__ bnshift,
                                                    float* __restrict__ y2,
                                                    float* __restrict__ hinsum,
                                                    float* __restrict__ hinsumsq){
  __shared__ float ls[3][WW+2];
  __shared__ __align__(16) float lw[9*CF];
  __shared__ float part[32][2][4];
  int t = threadIdx.x, lane = t & 63, wv = t >> 6;
  int nh = blockIdx.x, n = nh / HH, h = nh % HH;
  float acc[CF];
  #pragma unroll
  for (int c = 0; c < CF; ++c) acc[c] = 0.f;
  const float* yn = y1 + (size_t)n*C*HW;
  conv_core<CF, true>(yn, wTf, h, t, acc, ls, lw);

  // BN affine + softmax over 72 channels (all in registers, fully unrolled)
  float m = -1e30f;
  #pragma unroll
  for (int c = 0; c < CF; ++c){ acc[c] = acc[c]*bnscale[c] + bnshift[c]; m = fmaxf(m, acc[c]); }
  float s = 0.f;
  #pragma unroll
  for (int c = 0; c < CF; ++c){ acc[c] = __expf(acc[c] - m); s += acc[c]; }
  float inv = 1.f / s;
  #pragma unroll
  for (int c = 0; c < CF; ++c) acc[c] *= inv;

  // filter: out[c] = y1[c] - sum_k sig[g*9+k] * y1_reflect[k-th neighbor]
  float* y2n = y2 + (size_t)n*C*HW;
  #pragma unroll
  for (int c = 0; c < C; ++c){
    __syncthreads();
    #pragma unroll
    for (int r = 0; r < 3; ++r){
      int hh = h + r - 1;
      hh = (hh < 0) ? 1 : ((hh >= HH) ? (HH-2) : hh);
      const float* row = yn + c*HW + hh*WW;
      ls[r][t+1] = row[t];
      if (t == 0)   ls[r][0]     = row[1];
      if (t == 255) ls[r][WW+1]  = row[WW-2];
    }
    __syncthreads();
    const int g = c >> 3;
    float f = ls[1][t+1];
    #pragma unroll
    for (int k = 0; k < 9; ++k){
      float v = ls[k/3][t + (k%3)];
      f -= acc[g*9 + k] * v;
    }
    y2n[c*HW + h*WW + t] = f;
    if (c < 32){
      float ss = f, qq = f*f;
      #pragma unroll
      for (int d = 32; d; d >>= 1){ ss += __shfl_xor(ss, d); qq += __shfl_xor(qq, d); }
      if (lane == 0){ part[c][0][wv] = ss; part[c][1][wv] = qq; }
    }
  }
  __syncthreads();
  if (t < 64){
    int c = t >> 1, which = t & 1;
    float ss = part[c][which][0] + part[c][which][1] + part[c][which][2] + part[c][which][3];
    atomicAdd(which ? &hinsumsq[n*32 + c] : &hinsum[n*32 + c], ss);
  }
}

// ---------------- HIN stat finalize ----------------
__global__ void hinstats_kernel(const float* __restrict__ hinsum, const float* __restrict__ hinsumsq,
                                float* __restrict__ hmu, float* __restrict__ hrs){
  int i = threadIdx.x;
  if (i < NN*32){
    const float M = (float)HW;
    float mu  = hinsum[i] / M;
    float var = hinsumsq[i] / M - mu*mu;
    hmu[i] = mu;
    hrs[i] = rsqrtf(var + EPSV);
  }
}

// ---------------- HIN apply + leaky (in place on y2) ----------------
__global__ __launch_bounds__(256) void hinapply_kernel(float* __restrict__ y2,
                                                       const float* __restrict__ hmu,
                                                       const float* __restrict__ hrs){
  size_t i = ((size_t)blockIdx.x*256 + threadIdx.x) * 4;
  const size_t total = (size_t)NN*C*HW;
  if (i >= total) return;
  float4 v = *reinterpret_cast<float4*>(y2 + i);
  int nc = (int)(i / HW);
  int cc = nc % C, n = nc / C;
  if (cc < 32){
    float mu = hmu[n*32 + cc], rs = hrs[n*32 + cc];
    v.x = (v.x - mu)*rs; v.y = (v.y - mu)*rs; v.z = (v.z - mu)*rs; v.w = (v.w - mu)*rs;
  }
  v.x = leakyf(v.x); v.y = leakyf(v.y); v.z = leakyf(v.z); v.w = leakyf(v.w);
  *reinterpret_cast<float4*>(y2 + i) = v;
}

// ---------------- conv2 + leaky + 1x1 residual conv + final add ----------------
__global__ __launch_bounds__(256) void conv2_kernel(const float* __restrict__ y2,
                                                    const float* __restrict__ wT2,
                                                    const float* __restrict__ b2,
                                                    const float* __restrict__ x,
                                                    const float* __restrict__ wrT,
                                                    const float* __restrict__ br,
                                                    float* __restrict__ out){
  __shared__ float ls[3][WW+2];
  __shared__ __align__(16) float lw[9*C];
  __shared__ __align__(16) float lwr[C*C];
  int t = threadIdx.x;
  int nh = blockIdx.x, n = nh / HH, h = nh % HH;
  for (int j = t; j < C*C; j += 256) lwr[j] = wrT[j];   // covered by conv_core's first __syncthreads
  float acc[C];
  #pragma unroll
  for (int co = 0; co < C; ++co) acc[co] = b2[co];
  conv_core<C, false>(y2 + (size_t)n*C*HW, wT2, h, t, acc, ls, lw);
  #pragma unroll
  for (int co = 0; co < C; ++co) acc[co] = leakyf(acc[co]);
  // residual 1x1 conv on x
  const float* xn = x + (size_t)n*C*HW + h*WW + t;
  for (int ci = 0; ci < C; ++ci){
    float xa = xn[ci*HW];
    const float4* w4 = reinterpret_cast<const float4*>(lwr + ci*C);
    #pragma unroll
    for (int q = 0; q < C/4; ++q){
      float4 wv = w4[q];
      acc[4*q+0] = fmaf(xa, wv.x, acc[4*q+0]);
      acc[4*q+1] = fmaf(xa, wv.y, acc[4*q+1]);
      acc[4*q+2] = fmaf(xa, wv.z, acc[4*q+2]);
      acc[4*q+3] = fmaf(xa, wv.w, acc[4*q+3]);
    }
  }
  float* on = out + (size_t)n*C*HW + h*WW + t;
  #pragma unroll
  for (int co = 0; co < C; ++co) on[co*HW] = acc[co] + br[co];
}

extern "C" void kernel_launch(void* const* d_in, const int* in_sizes, int n_in,
                              void* d_out, int out_size, void* d_ws, size_t ws_size,
                              hipStream_t stream){
  const float* x     = (const float*)d_in[0];
  const float* w1    = (const float*)d_in[1];
  const float* b1    = (const float*)d_in[2];
  const float* wf    = (const float*)d_in[3];
  const float* gamma = (const float*)d_in[4];
  const float* beta  = (const float*)d_in[5];
  const float* w2    = (const float*)d_in[6];
  const float* b2    = (const float*)d_in[7];
  const float* wr    = (const float*)d_in[8];
  const float* br    = (const float*)d_in[9];
  float* out = (float*)d_out;
  float* ws  = (float*)d_ws;

  float* y2    = ws;                                   // N*C*H*W
  float* stats = ws + (size_t)NN*C*HW;                 // 1024 floats
  float* sigsum   = stats;
  float* sigsumsq = stats + 72;
  float* bnscale  = stats + 144;
  float* bnshift  = stats + 216;
  float* hinsum   = stats + 288;   // 128
  float* hinsumsq = stats + 416;   // 128
  float* hmu      = stats + 544;   // 128
  float* hrs      = stats + 672;   // 128
  float* wT1 = stats + 1024;       // 36864
  float* wTf = wT1 + C*C*9;        // 41472
  float* wT2 = wTf + CF*C*9;       // 36864
  float* wrT = wT2 + C*C*9;        // 4096
  float* y1  = out;                // d_out doubles as y1 scratch

  hipMemsetAsync(stats, 0, 1024*sizeof(float), stream);
  prep_weights<<<162, 256, 0, stream>>>(w1, wf, w2, wr, wT1, wTf, wT2, wrT);
  conv1_kernel<<<NN*HH, 256, 0, stream>>>(x, wT1, b1, y1);
  passA_kernel<<<NN*HH, 256, 0, stream>>>(y1, wTf, sigsum, sigsumsq);
  bnstats_kernel<<<1, 128, 0, stream>>>(sigsum, sigsumsq, gamma, beta, bnscale, bnshift);
  passB_kernel<<<NN*HH, 256, 0, stream>>>(y1, wTf, bnscale, bnshift, y2, hinsum, hinsumsq);
  hinstats_kernel<<<1, 128, 0, stream>>>(hinsum, hinsumsq, hmu, hrs);
  hinapply_kernel<<<(NN*C*HW/4 + 255)/256, 256, 0, stream>>>(y2, hmu, hrs);
  conv2_kernel<<<NN*HH, 256, 0, stream>>>(y2, wT2, b2, x, wrT, br, out);
}

// Round 2
// 765.001 us; speedup vs baseline: 2.7710x; 2.7710x over previous
//
#include <hip/hip_runtime.h>

typedef unsigned short u16;
typedef __attribute__((ext_vector_type(8))) short bf16x8;
typedef __attribute__((ext_vector_type(4))) float f32x4;

#define NN 4
#define HH 256
#define WW 256
#define PD 258
#define CIN 64
#define EPSV 1e-5f

__device__ __forceinline__ float b2f(u16 x){ union{unsigned u; float f;} q; q.u = ((unsigned)x)<<16; return q.f; }
__device__ __forceinline__ u16 f2b(float f){ union{float f; unsigned u;} q; q.f = f; unsigned r = q.u + 0x7FFF + ((q.u>>16)&1u); return (u16)(r>>16); }
__device__ __forceinline__ float leakyf(float x){ return x >= 0.f ? x : 0.01f*x; }

// ---------- prep: weights OIHW f32 -> [tap][cout][cin] bf16 ----------
__global__ void prep_kernel(const float* __restrict__ w1, const float* __restrict__ wf,
                            const float* __restrict__ w2, const float* __restrict__ wr,
                            u16* __restrict__ wB1, u16* __restrict__ wBf,
                            u16* __restrict__ wB2, u16* __restrict__ wBr){
  int idx = blockIdx.x*256 + threadIdx.x;
  if (idx < 9*64*64){
    int tap = idx/4096, r = idx%4096, cout = r/64, cin = r%64;
    int src = (cout*64 + cin)*9 + tap;
    wB1[idx] = f2b(w1[src]);
    wB2[idx] = f2b(w2[src]);
  }
  if (idx < 9*80*64){
    int tap = idx/5120, r = idx%5120, cout = r/64, cin = r%64;
    float v = (cout < 72) ? wf[(cout*64 + cin)*9 + tap] : 0.f;
    wBf[idx] = f2b(v);
  }
  if (idx < 64*64){
    int cout = idx/64, cin = idx%64;
    wBr[idx] = f2b(wr[cout*64 + cin]);
  }
}

// ---------- pad_x: x NCHW f32 -> xpad NHWC bf16 [n][258][258][64], zero borders ----------
__global__ __launch_bounds__(256) void padx_kernel(const float* __restrict__ x, u16* __restrict__ xpad){
  int n = blockIdx.x >> 8, h = blockIdx.x & 255, t = threadIdx.x;
  u16* dstrow = xpad + ((size_t)(n*PD + h + 1)*PD)*CIN;
  const uint4 z = {0,0,0,0};
  #pragma unroll
  for (int c8 = 0; c8 < 8; ++c8){
    u16 buf[8];
    #pragma unroll
    for (int j = 0; j < 8; ++j)
      buf[j] = f2b(x[((size_t)(n*64 + c8*8 + j))*65536 + h*256 + t]);
    *(uint4*)(dstrow + (size_t)(t+1)*CIN + c8*8) = *(uint4*)buf;
  }
  if (t == 0)   { for (int c8 = 0; c8 < 8; ++c8) *(uint4*)(dstrow + 0*CIN   + c8*8) = z; }
  if (t == 255) { for (int c8 = 0; c8 < 8; ++c8) *(uint4*)(dstrow + 257*CIN + c8*8) = z; }
  if (h == 0 || h == 255){
    u16* brow = xpad + ((size_t)(n*PD + (h == 0 ? 0 : 257))*PD)*CIN;
    for (int p = t; p < PD; p += 256)
      for (int c8 = 0; c8 < 8; ++c8) *(uint4*)(brow + (size_t)p*CIN + c8*8) = z;
  }
}

// ---------- MFMA conv core ----------
// MODE 0: conv1 (A=xpad, +bias, out=y1pad interior bf16)
// MODE 1: convF (A=y1pad, no bias, out=sig [n][hw][80] bf16)
// MODE 2: conv2 (A=y2pad w/ HIN+leaky transform in staging, epilogue leaky(+b2) + 1x1(xpad,wBr) + br -> f32 NCHW)
template<int NF, int MODE>
__global__ __launch_bounds__(256,2) void conv_mfma(
    const u16* __restrict__ Ain, const u16* __restrict__ wB, const float* __restrict__ bias,
    u16* __restrict__ outB, float* __restrict__ outF,
    const u16* __restrict__ xpad, const u16* __restrict__ wBr,
    const float* __restrict__ br, const float* __restrict__ hmu, const float* __restrict__ hrs){

  constexpr int NC = NF*16;
  __shared__ __align__(16) u16 As[3*130*64];
  __shared__ __align__(16) u16 Bx[128*NC];   // Ob (MODE<2) or Xs (MODE==2, uses 128*64)

  int t = threadIdx.x, lane = t & 63, wv = t >> 6;
  int bid = blockIdx.x;
  int n = bid >> 9, r = bid & 511, h = r >> 1, wt = r & 1, w0 = wt*128;

  // ---- stage A window: rows h..h+2 (padded), cols w0..w0+129, swizzled chunks ----
  const u16* Abase = Ain + ((size_t)(n*PD + h)*PD + w0)*CIN;
  for (int idx = t; idx < 3120; idx += 256){
    int rr = idx/1040, rem = idx - rr*1040, pc = rem >> 3, cc = rem & 7;
    uint4 v = *(const uint4*)(Abase + (size_t)rr*PD*CIN + (size_t)pc*CIN + cc*8);
    if (MODE == 2){
      int gpr = h + rr, gpc = w0 + pc;
      if (gpr == 0 || gpr == 257 || gpc == 0 || gpc == 257){
        v.x = v.y = v.z = v.w = 0;
      } else {
        u16* e = (u16*)&v;
        #pragma unroll
        for (int j = 0; j < 8; ++j){
          int c = cc*8 + j;
          float f = b2f(e[j]);
          if (c < 32) f = (f - hmu[n*32 + c]) * hrs[n*32 + c];
          e[j] = f2b(leakyf(f));
        }
      }
    }
    *(uint4*)((char*)As + (((rr*130 + pc) << 7) + ((cc ^ (pc & 7)) << 4))) = v;
  }
  if (MODE == 2){
    const u16* Xbase = xpad + ((size_t)(n*PD + h + 1)*PD + w0 + 1)*CIN;
    for (int idx = t; idx < 1024; idx += 256){
      int px = idx >> 3, cc = idx & 7;
      uint4 v = *(const uint4*)(Xbase + (size_t)px*CIN + cc*8);
      *(uint4*)((char*)Bx + ((px << 7) + ((cc ^ (px & 7)) << 4))) = v;
    }
  }
  __syncthreads();

  int l15 = lane & 15, l4 = lane >> 4;
  int wm = wv;                       // wave owns pixels [wm*32, wm*32+32)
  f32x4 acc[2][NF];
  #pragma unroll
  for (int mf = 0; mf < 2; ++mf)
    #pragma unroll
    for (int f = 0; f < NF; ++f) acc[mf][f] = (f32x4){0.f,0.f,0.f,0.f};

  #pragma unroll
  for (int tap = 0; tap < 9; ++tap){
    const int dh = tap/3, dw = tap%3;
    bf16x8 bf[2][NF];
    #pragma unroll
    for (int ks = 0; ks < 2; ++ks)
      #pragma unroll
      for (int f = 0; f < NF; ++f)
        bf[ks][f] = *(const bf16x8*)(wB + ((size_t)(tap*NC + f*16 + l15))*64 + ks*32 + l4*8);
    #pragma unroll
    for (int ks = 0; ks < 2; ++ks){
      #pragma unroll
      for (int mf = 0; mf < 2; ++mf){
        int wl = wm*32 + mf*16 + l15 + dw;
        int cc = ks*4 + l4;
        bf16x8 af = *(const bf16x8*)((const char*)As + (((dh*130 + wl) << 7) + ((cc ^ (wl & 7)) << 4)));
        #pragma unroll
        for (int f = 0; f < NF; ++f)
          acc[mf][f] = __builtin_amdgcn_mfma_f32_16x16x32_bf16(af, bf[ks][f], acc[mf][f], 0, 0, 0);
      }
    }
  }

  if (MODE < 2){
    // write acc -> Ob (bf16), then coalesced copy out
    #pragma unroll
    for (int mf = 0; mf < 2; ++mf)
      #pragma unroll
      for (int f = 0; f < NF; ++f){
        int cout = f*16 + l15;
        float bv = (MODE == 0) ? bias[cout] : 0.f;
        #pragma unroll
        for (int reg = 0; reg < 4; ++reg){
          int px = wm*32 + mf*16 + l4*4 + reg;
          Bx[px*NC + cout] = f2b(acc[mf][f][reg] + bv);
        }
      }
    __syncthreads();
    const int nch = NC/8;
    for (int idx = t; idx < 128*nch; idx += 256){
      int px = idx/nch, c8 = idx - px*nch;
      uint4 v = *(const uint4*)(Bx + px*NC + c8*8);
      if (MODE == 0)
        *(uint4*)(outB + ((size_t)(n*PD + h + 1)*PD + (w0 + 1 + px))*CIN + c8*8) = v;
      else
        *(uint4*)(outB + ((size_t)(n*65536 + h*256 + w0 + px))*80 + c8*8) = v;
    }
  } else {
    // leaky(conv + b2), then residual 1x1 on xpad, then +br, store f32 NCHW
    #pragma unroll
    for (int mf = 0; mf < 2; ++mf)
      #pragma unroll
      for (int f = 0; f < NF; ++f){
        float bv = bias[f*16 + l15];
        #pragma unroll
        for (int reg = 0; reg < 4; ++reg)
          acc[mf][f][reg] = leakyf(acc[mf][f][reg] + bv);
      }
    f32x4 racc[2][NF];
    #pragma unroll
    for (int mf = 0; mf < 2; ++mf)
      #pragma unroll
      for (int f = 0; f < NF; ++f) racc[mf][f] = (f32x4){0.f,0.f,0.f,0.f};
    bf16x8 brf[2][NF];
    #pragma unroll
    for (int ks = 0; ks < 2; ++ks)
      #pragma unroll
      for (int f = 0; f < NF; ++f)
        brf[ks][f] = *(const bf16x8*)(wBr + ((size_t)(f*16 + l15))*64 + ks*32 + l4*8);
    #pragma unroll
    for (int ks = 0; ks < 2; ++ks)
      #pragma unroll
      for (int mf = 0; mf < 2; ++mf){
        int wl = wm*32 + mf*16 + l15;
        int cc = ks*4 + l4;
        bf16x8 xf = *(const bf16x8*)((const char*)Bx + (((wl) << 7) + ((cc ^ (wl & 7)) << 4)));
        #pragma unroll
        for (int f = 0; f < NF; ++f)
          racc[mf][f] = __builtin_amdgcn_mfma_f32_16x16x32_bf16(xf, brf[ks][f], racc[mf][f], 0, 0, 0);
      }
    #pragma unroll
    for (int mf = 0; mf < 2; ++mf)
      #pragma unroll
      for (int f = 0; f < NF; ++f){
        int cout = f*16 + l15;
        float bb = br[cout];
        float4 o;
        o.x = acc[mf][f][0] + racc[mf][f][0] + bb;
        o.y = acc[mf][f][1] + racc[mf][f][1] + bb;
        o.z = acc[mf][f][2] + racc[mf][f][2] + bb;
        o.w = acc[mf][f][3] + racc[mf][f][3] + bb;
        int px = wm*32 + mf*16 + l4*4;
        *(float4*)(outF + ((size_t)(n*64 + cout))*65536 + h*256 + w0 + px) = o;
      }
  }
}

// ---------- reflect borders of y1pad ----------
__global__ void reflect_kernel(u16* __restrict__ y1pad){
  int idx = blockIdx.x*256 + threadIdx.x;
  if (idx >= 4*1028*8) return;
  int n = idx/(1028*8), rem = idx%(1028*8), p = rem >> 3, cc = rem & 7;
  int pr, pc;
  if      (p < 258)  { pr = 0;   pc = p; }
  else if (p < 516)  { pr = 257; pc = p - 258; }
  else if (p < 772)  { pr = 1 + (p - 516); pc = 0; }
  else               { pr = 1 + (p - 772); pc = 257; }
  int sr = (pr == 0) ? 2 : ((pr == 257) ? 255 : pr);
  int sc = (pc == 0) ? 2 : ((pc == 257) ? 255 : pc);
  uint4 v = *(const uint4*)(y1pad + ((size_t)(n*PD + sr)*PD + sc)*CIN + cc*8);
  *(uint4*)(y1pad + ((size_t)(n*PD + pr)*PD + pc)*CIN + cc*8) = v;
}

// ---------- BN stat reduce over sig ----------
__global__ __launch_bounds__(256) void bnreduce_kernel(const u16* __restrict__ sig,
                                                       float* __restrict__ bnsum, float* __restrict__ bnsumsq){
  __shared__ float ssum[80], ssq[80];
  int t = threadIdx.x;
  if (t < 80){ ssum[t] = 0.f; ssq[t] = 0.f; }
  __syncthreads();
  size_t base = (size_t)blockIdx.x * 128 * 80;
  for (int idx = t; idx < 128*80; idx += 256){
    int c = idx % 80;
    if (c < 72){
      float v = b2f(sig[base + idx]);
      atomicAdd(&ssum[c], v);
      atomicAdd(&ssq[c], v*v);
    }
  }
  __syncthreads();
  if (t < 72){ atomicAdd(&bnsum[t], ssum[t]); atomicAdd(&bnsumsq[t], ssq[t]); }
}

__global__ void bnfinal_kernel(const float* __restrict__ bnsum, const float* __restrict__ bnsumsq,
                               const float* __restrict__ gamma, const float* __restrict__ beta,
                               float* __restrict__ bnscale, float* __restrict__ bnshift){
  int c = threadIdx.x;
  if (c < 72){
    const float M = 262144.f;
    float mu  = bnsum[c] / M;
    float var = bnsumsq[c] / M - mu*mu;
    float sc  = gamma[c] * rsqrtf(var + EPSV);
    bnscale[c] = sc;
    bnshift[c] = beta[c] - mu*sc;
  }
}

// ---------- filter: BN+softmax(72)+spatial filter -> y2pad interior ----------
__global__ __launch_bounds__(256,2) void filter_kernel(const u16* __restrict__ sig,
                                                       const u16* __restrict__ y1pad,
                                                       const float* __restrict__ bnscale,
                                                       const float* __restrict__ bnshift,
                                                       u16* __restrict__ y2pad){
  __shared__ float sc[72], sh[72];
  int t = threadIdx.x;
  if (t < 72){ sc[t] = bnscale[t]; sh[t] = bnshift[t]; }
  __syncthreads();
  int n = blockIdx.x >> 8, h = blockIdx.x & 255;

  float sv[72];
  const u16* sp = sig + ((size_t)(n*65536 + h*256 + t))*80;
  #pragma unroll
  for (int i = 0; i < 9; ++i){
    uint4 v = *(const uint4*)(sp + i*8);
    const u16* e = (const u16*)&v;
    #pragma unroll
    for (int j = 0; j < 8; ++j) sv[i*8+j] = b2f(e[j]);
  }
  float mx = -1e30f;
  #pragma unroll
  for (int c = 0; c < 72; ++c){ sv[c] = sv[c]*sc[c] + sh[c]; mx = fmaxf(mx, sv[c]); }
  float sum = 0.f;
  #pragma unroll
  for (int c = 0; c < 72; ++c){ sv[c] = __expf(sv[c] - mx); sum += sv[c]; }
  float inv = -1.f/sum;
  #pragma unroll
  for (int c = 0; c < 72; ++c) sv[c] *= inv;          // sv = -softmax
  #pragma unroll
  for (int g = 0; g < 8; ++g) sv[g*9+4] += 1.f;       // kern = delta - softmax

  #pragma unroll
  for (int g = 0; g < 8; ++g){
    float o[8] = {0,0,0,0,0,0,0,0};
    #pragma unroll
    for (int i = 0; i < 3; ++i)
      #pragma unroll
      for (int j = 0; j < 3; ++j){
        uint4 v = *(const uint4*)(y1pad + ((size_t)(n*PD + h + i)*PD + (t + j))*CIN + g*8);
        const u16* e = (const u16*)&v;
        float k = sv[g*9 + i*3 + j];
        #pragma unroll
        for (int jj = 0; jj < 8; ++jj) o[jj] = fmaf(k, b2f(e[jj]), o[jj]);
      }
    u16 ob[8];
    #pragma unroll
    for (int jj = 0; jj < 8; ++jj) ob[jj] = f2b(o[jj]);
    *(uint4*)(y2pad + ((size_t)(n*PD + h + 1)*PD + (t + 1))*CIN + g*8) = *(uint4*)ob;
  }
}

// ---------- HIN stat reduce over y2pad interior (channels 0..31) ----------
__global__ __launch_bounds__(256) void hinreduce_kernel(const u16* __restrict__ y2pad,
                                                        float* __restrict__ hinsum, float* __restrict__ hinsumsq){
  __shared__ float ps[4][32][2];
  int t = threadIdx.x, n = blockIdx.x >> 8, h = blockIdx.x & 255;
  int c = t & 31, pg = t >> 5;   // 8 pixel groups
  float s = 0.f, q = 0.f;
  const u16* rowp = y2pad + ((size_t)(n*PD + h + 1)*PD + 1)*CIN;
  for (int i = 0; i < 32; ++i){
    int px = pg + 8*i;
    float v = b2f(rowp[(size_t)px*CIN + c]);
    s += v; q += v*v;
  }
  s += __shfl_xor(s, 32); q += __shfl_xor(q, 32);
  int wv = t >> 6, lane = t & 63;
  if (lane < 32){ ps[wv][lane][0] = s; ps[wv][lane][1] = q; }
  __syncthreads();
  if (t < 32){
    float ts = ps[0][t][0] + ps[1][t][0] + ps[2][t][0] + ps[3][t][0];
    float tq = ps[0][t][1] + ps[1][t][1] + ps[2][t][1] + ps[3][t][1];
    atomicAdd(&hinsum[n*32 + t], ts);
    atomicAdd(&hinsumsq[n*32 + t], tq);
  }
}

__global__ void hinfinal_kernel(const float* __restrict__ hinsum, const float* __restrict__ hinsumsq,
                                float* __restrict__ hmu, float* __restrict__ hrs){
  int i = threadIdx.x;
  if (i < 128){
    const float M = 65536.f;
    float mu  = hinsum[i] / M;
    float var = hinsumsq[i] / M - mu*mu;
    hmu[i] = mu;
    hrs[i] = rsqrtf(var + EPSV);
  }
}

// ---------- launch ----------
extern "C" void kernel_launch(void* const* d_in, const int* in_sizes, int n_in,
                              void* d_out, int out_size, void* d_ws, size_t ws_size,
                              hipStream_t stream){
  const float* x     = (const float*)d_in[0];
  const float* w1    = (const float*)d_in[1];
  const float* b1    = (const float*)d_in[2];
  const float* wf    = (const float*)d_in[3];
  const float* gamma = (const float*)d_in[4];
  const float* beta  = (const float*)d_in[5];
  const float* w2    = (const float*)d_in[6];
  const float* b2    = (const float*)d_in[7];
  const float* wr    = (const float*)d_in[8];
  const float* br    = (const float*)d_in[9];

  char* ws = (char*)d_ws;
  const size_t PADB = (size_t)NN*PD*PD*CIN*2;   // 34,080,768 bytes
  u16* xpad  = (u16*)(ws);
  u16* y1pad = (u16*)(ws + PADB);
  u16* y2pad = (u16*)(ws + 2*PADB);
  float* stats = (float*)(ws + 3*PADB);
  float* bnsum   = stats;        float* bnsumsq = stats + 80;
  float* bnscale = stats + 160;  float* bnshift = stats + 240;
  float* hinsum  = stats + 320;  float* hinsumsq= stats + 448;
  float* hmu     = stats + 576;  float* hrs     = stats + 704;
  u16* wB1 = (u16*)(ws + 3*PADB + 4096);
  u16* wBf = wB1 + 9*64*64;
  u16* wB2 = wBf + 9*80*64;
  u16* wBr = wB2 + 9*64*64;

  u16* sig = (u16*)d_out;        // 41.9MB bf16, overwritten by conv2's f32 output later
  float* out = (float*)d_out;

  hipMemsetAsync(stats, 0, 4096, stream);
  prep_kernel<<<180, 256, 0, stream>>>(w1, wf, w2, wr, wB1, wBf, wB2, wBr);
  padx_kernel<<<NN*HH, 256, 0, stream>>>(x, xpad);
  conv_mfma<4,0><<<2048, 256, 0, stream>>>(xpad, wB1, b1, y1pad, nullptr, nullptr, nullptr, nullptr, nullptr, nullptr);
  reflect_kernel<<<(4*1028*8 + 255)/256, 256, 0, stream>>>(y1pad);
  conv_mfma<5,1><<<2048, 256, 0, stream>>>(y1pad, wBf, nullptr, sig, nullptr, nullptr, nullptr, nullptr, nullptr, nullptr);
  bnreduce_kernel<<<2048, 256, 0, stream>>>(sig, bnsum, bnsumsq);
  bnfinal_kernel<<<1, 80, 0, stream>>>(bnsum, bnsumsq, gamma, beta, bnscale, bnshift);
  filter_kernel<<<NN*HH, 256, 0, stream>>>(sig, y1pad, bnscale, bnshift, y2pad);
  hinreduce_kernel<<<NN*HH, 256, 0, stream>>>(y2pad, hinsum, hinsumsq);
  hinfinal_kernel<<<1, 128, 0, stream>>>(hinsum, hinsumsq, hmu, hrs);
  conv_mfma<4,2><<<2048, 256, 0, stream>>>(y2pad, wB2, b2, nullptr, out, xpad, wBr, br, hmu, hrs);
}

// Round 3
// 569.061 us; speedup vs baseline: 3.7252x; 1.3443x over previous
//
#include <hip/hip_runtime.h>

typedef unsigned short u16;
typedef __attribute__((ext_vector_type(8))) short bf16x8;
typedef __attribute__((ext_vector_type(4))) float f32x4;

#define NN 4
#define HH 256
#define WW 256
#define PD 258
#define CIN 64
#define EPSV 1e-5f

__device__ __forceinline__ float b2f(u16 x){ union{unsigned u; float f;} q; q.u = ((unsigned)x)<<16; return q.f; }
__device__ __forceinline__ u16 f2b(float f){ union{float f; unsigned u;} q; q.f = f; unsigned r = q.u + 0x7FFF + ((q.u>>16)&1u); return (u16)(r>>16); }
__device__ __forceinline__ float leakyf(float x){ return x >= 0.f ? x : 0.01f*x; }

// ---------- prep: weights OIHW f32 -> [tap][cout][cin] bf16 ----------
__global__ void prep_kernel(const float* __restrict__ w1, const float* __restrict__ wf,
                            const float* __restrict__ w2, const float* __restrict__ wr,
                            u16* __restrict__ wB1, u16* __restrict__ wBf,
                            u16* __restrict__ wB2, u16* __restrict__ wBr){
  int idx = blockIdx.x*256 + threadIdx.x;
  if (idx < 9*64*64){
    int tap = idx/4096, r = idx%4096, cout = r/64, cin = r%64;
    int src = (cout*64 + cin)*9 + tap;
    wB1[idx] = f2b(w1[src]);
    wB2[idx] = f2b(w2[src]);
  }
  if (idx < 9*80*64){
    int tap = idx/5120, r = idx%5120, cout = r/64, cin = r%64;
    float v = (cout < 72) ? wf[(cout*64 + cin)*9 + tap] : 0.f;
    wBf[idx] = f2b(v);
  }
  if (idx < 64*64){
    int cout = idx/64, cin = idx%64;
    wBr[idx] = f2b(wr[cout*64 + cin]);
  }
}

// ---------- pad_x: x NCHW f32 -> xpad NHWC bf16 [n][258][258][64], zero borders ----------
__global__ __launch_bounds__(256) void padx_kernel(const float* __restrict__ x, u16* __restrict__ xpad){
  int n = blockIdx.x >> 8, h = blockIdx.x & 255, t = threadIdx.x;
  u16* dstrow = xpad + ((size_t)(n*PD + h + 1)*PD)*CIN;
  const uint4 z = {0,0,0,0};
  #pragma unroll
  for (int c8 = 0; c8 < 8; ++c8){
    u16 buf[8];
    #pragma unroll
    for (int j = 0; j < 8; ++j)
      buf[j] = f2b(x[((size_t)(n*64 + c8*8 + j))*65536 + h*256 + t]);
    *(uint4*)(dstrow + (size_t)(t+1)*CIN + c8*8) = *(uint4*)buf;
  }
  if (t == 0)   { for (int c8 = 0; c8 < 8; ++c8) *(uint4*)(dstrow + 0*CIN   + c8*8) = z; }
  if (t == 255) { for (int c8 = 0; c8 < 8; ++c8) *(uint4*)(dstrow + 257*CIN + c8*8) = z; }
  if (h == 0 || h == 255){
    u16* brow = xpad + ((size_t)(n*PD + (h == 0 ? 0 : 257))*PD)*CIN;
    for (int p = t; p < PD; p += 256)
      for (int c8 = 0; c8 < 8; ++c8) *(uint4*)(brow + (size_t)p*CIN + c8*8) = z;
  }
}

// ---------- MFMA conv core ----------
// MODE 0: conv1 (A=xpad zero-padded, +bias, out=y1pad interior bf16)
// MODE 1: convF (A=y1pad w/ reflect mapping in staging, out=sig [n][hw][80] bf16, + BN sum/sumsq atomics)
// MODE 2: conv2 (A=y2pad w/ HIN+leaky in staging, epilogue leaky(+b2) + 1x1(xpad,wBr) + br -> f32 NCHW)
template<int NF, int MODE>
__global__ __launch_bounds__(256,2) void conv_mfma(
    const u16* __restrict__ Ain, const u16* __restrict__ wB, const float* __restrict__ bias,
    u16* __restrict__ outB, float* __restrict__ outF,
    const u16* __restrict__ xpad, const u16* __restrict__ wBr,
    const float* __restrict__ br, const float* __restrict__ hmu, const float* __restrict__ hrs,
    float* __restrict__ bnsum, float* __restrict__ bnsumsq){

  constexpr int NC = NF*16;
  __shared__ __align__(16) u16 As[3*130*64];
  __shared__ __align__(16) u16 Bx[128*NC];   // Ob (MODE<2) or Xs (MODE==2, uses 128*64)
  __shared__ float bnpart[4][NF][16][2];

  int t = threadIdx.x, lane = t & 63, wv = t >> 6;
  int bid = blockIdx.x;
  int n = bid >> 9, r = bid & 511, h = r >> 1, wt = r & 1, w0 = wt*128;

  // ---- stage A window: rows h..h+2 (padded coords), cols w0..w0+129, swizzled chunks ----
  const u16* Abase = Ain + ((size_t)(n*PD + h)*PD + w0)*CIN;
  for (int idx = t; idx < 3120; idx += 256){
    int rr = idx/1040, rem = idx - rr*1040, pc = rem >> 3, cc = rem & 7;
    const u16* src;
    if (MODE == 1){
      int ir = h + rr - 1;  ir = (ir < 0) ? 1 : (ir > 255 ? 254 : ir);
      int ic = w0 + pc - 1; ic = (ic < 0) ? 1 : (ic > 255 ? 254 : ic);
      src = Ain + ((size_t)(n*PD + ir + 1)*PD + (ic + 1))*CIN + cc*8;
    } else {
      src = Abase + (size_t)rr*PD*CIN + (size_t)pc*CIN + cc*8;
    }
    uint4 v = *(const uint4*)src;
    if (MODE == 2){
      int gpr = h + rr, gpc = w0 + pc;
      if (gpr == 0 || gpr == 257 || gpc == 0 || gpc == 257){
        v.x = v.y = v.z = v.w = 0;
      } else {
        u16* e = (u16*)&v;
        #pragma unroll
        for (int j = 0; j < 8; ++j){
          int c = cc*8 + j;
          float f = b2f(e[j]);
          if (c < 32) f = (f - hmu[n*32 + c]) * hrs[n*32 + c];
          e[j] = f2b(leakyf(f));
        }
      }
    }
    *(uint4*)((char*)As + (((rr*130 + pc) << 7) + ((cc ^ (pc & 7)) << 4))) = v;
  }
  if (MODE == 2){
    const u16* Xbase = xpad + ((size_t)(n*PD + h + 1)*PD + w0 + 1)*CIN;
    for (int idx = t; idx < 1024; idx += 256){
      int px = idx >> 3, cc = idx & 7;
      uint4 v = *(const uint4*)(Xbase + (size_t)px*CIN + cc*8);
      *(uint4*)((char*)Bx + ((px << 7) + ((cc ^ (px & 7)) << 4))) = v;
    }
  }
  __syncthreads();

  int l15 = lane & 15, l4 = lane >> 4;
  int wm = wv;                       // wave owns pixels [wm*32, wm*32+32)
  f32x4 acc[2][NF];
  #pragma unroll
  for (int mf = 0; mf < 2; ++mf)
    #pragma unroll
    for (int f = 0; f < NF; ++f) acc[mf][f] = (f32x4){0.f,0.f,0.f,0.f};

  #pragma unroll
  for (int tap = 0; tap < 9; ++tap){
    const int dh = tap/3, dw = tap%3;
    bf16x8 bf[2][NF];
    #pragma unroll
    for (int ks = 0; ks < 2; ++ks)
      #pragma unroll
      for (int f = 0; f < NF; ++f)
        bf[ks][f] = *(const bf16x8*)(wB + ((size_t)(tap*NC + f*16 + l15))*64 + ks*32 + l4*8);
    #pragma unroll
    for (int ks = 0; ks < 2; ++ks){
      #pragma unroll
      for (int mf = 0; mf < 2; ++mf){
        int wl = wm*32 + mf*16 + l15 + dw;
        int cc = ks*4 + l4;
        bf16x8 af = *(const bf16x8*)((const char*)As + (((dh*130 + wl) << 7) + ((cc ^ (wl & 7)) << 4)));
        #pragma unroll
        for (int f = 0; f < NF; ++f)
          acc[mf][f] = __builtin_amdgcn_mfma_f32_16x16x32_bf16(af, bf[ks][f], acc[mf][f], 0, 0, 0);
      }
    }
  }

  if (MODE < 2){
    // BN partial stats (MODE 1): per-thread sum over its 8 pixels per cout, reduce over l4 lanes
    if (MODE == 1){
      #pragma unroll
      for (int f = 0; f < NF; ++f){
        float s = 0.f, q = 0.f;
        #pragma unroll
        for (int mf = 0; mf < 2; ++mf)
          #pragma unroll
          for (int reg = 0; reg < 4; ++reg){ float v = acc[mf][f][reg]; s += v; q += v*v; }
        s += __shfl_xor(s, 16); q += __shfl_xor(q, 16);
        s += __shfl_xor(s, 32); q += __shfl_xor(q, 32);
        if (l4 == 0){ bnpart[wv][f][l15][0] = s; bnpart[wv][f][l15][1] = q; }
      }
    }
    // write acc -> Ob (bf16), then coalesced copy out
    #pragma unroll
    for (int mf = 0; mf < 2; ++mf)
      #pragma unroll
      for (int f = 0; f < NF; ++f){
        int cout = f*16 + l15;
        float bv = (MODE == 0) ? bias[cout] : 0.f;
        #pragma unroll
        for (int reg = 0; reg < 4; ++reg){
          int px = wm*32 + mf*16 + l4*4 + reg;
          Bx[px*NC + cout] = f2b(acc[mf][f][reg] + bv);
        }
      }
    __syncthreads();
    const int nch = NC/8;
    for (int idx = t; idx < 128*nch; idx += 256){
      int px = idx/nch, c8 = idx - px*nch;
      uint4 v = *(const uint4*)(Bx + px*NC + c8*8);
      if (MODE == 0)
        *(uint4*)(outB + ((size_t)(n*PD + h + 1)*PD + (w0 + 1 + px))*CIN + c8*8) = v;
      else
        *(uint4*)(outB + ((size_t)(n*65536 + h*256 + w0 + px))*80 + c8*8) = v;
    }
    if (MODE == 1 && t < 160){
      int c = t >> 1, which = t & 1;
      if (c < 72){
        float v = bnpart[0][c>>4][c&15][which] + bnpart[1][c>>4][c&15][which]
                + bnpart[2][c>>4][c&15][which] + bnpart[3][c>>4][c&15][which];
        atomicAdd(which ? &bnsumsq[c] : &bnsum[c], v);
      }
    }
  } else {
    // leaky(conv + b2), then residual 1x1 on xpad, then +br, store f32 NCHW
    #pragma unroll
    for (int mf = 0; mf < 2; ++mf)
      #pragma unroll
      for (int f = 0; f < NF; ++f){
        float bv = bias[f*16 + l15];
        #pragma unroll
        for (int reg = 0; reg < 4; ++reg)
          acc[mf][f][reg] = leakyf(acc[mf][f][reg] + bv);
      }
    f32x4 racc[2][NF];
    #pragma unroll
    for (int mf = 0; mf < 2; ++mf)
      #pragma unroll
      for (int f = 0; f < NF; ++f) racc[mf][f] = (f32x4){0.f,0.f,0.f,0.f};
    bf16x8 brf[2][NF];
    #pragma unroll
    for (int ks = 0; ks < 2; ++ks)
      #pragma unroll
      for (int f = 0; f < NF; ++f)
        brf[ks][f] = *(const bf16x8*)(wBr + ((size_t)(f*16 + l15))*64 + ks*32 + l4*8);
    #pragma unroll
    for (int ks = 0; ks < 2; ++ks)
      #pragma unroll
      for (int mf = 0; mf < 2; ++mf){
        int wl = wm*32 + mf*16 + l15;
        int cc = ks*4 + l4;
        bf16x8 xf = *(const bf16x8*)((const char*)Bx + (((wl) << 7) + ((cc ^ (wl & 7)) << 4)));
        #pragma unroll
        for (int f = 0; f < NF; ++f)
          racc[mf][f] = __builtin_amdgcn_mfma_f32_16x16x32_bf16(xf, brf[ks][f], racc[mf][f], 0, 0, 0);
      }
    #pragma unroll
    for (int mf = 0; mf < 2; ++mf)
      #pragma unroll
      for (int f = 0; f < NF; ++f){
        int cout = f*16 + l15;
        float bb = br[cout];
        float4 o;
        o.x = acc[mf][f][0] + racc[mf][f][0] + bb;
        o.y = acc[mf][f][1] + racc[mf][f][1] + bb;
        o.z = acc[mf][f][2] + racc[mf][f][2] + bb;
        o.w = acc[mf][f][3] + racc[mf][f][3] + bb;
        int px = wm*32 + mf*16 + l4*4;
        *(float4*)(outF + ((size_t)(n*64 + cout))*65536 + h*256 + w0 + px) = o;
      }
  }
}

__global__ void bnfinal_kernel(const float* __restrict__ bnsum, const float* __restrict__ bnsumsq,
                               const float* __restrict__ gamma, const float* __restrict__ beta,
                               float* __restrict__ bnscale, float* __restrict__ bnshift){
  int c = threadIdx.x;
  if (c < 72){
    const float M = 262144.f;
    float mu  = bnsum[c] / M;
    float var = bnsumsq[c] / M - mu*mu;
    float sc  = gamma[c] * rsqrtf(var + EPSV);
    bnscale[c] = sc;
    bnshift[c] = beta[c] - mu*sc;
  }
}

// ---------- filter: BN+softmax(72)+spatial filter -> y2pad interior; + HIN partial stats ----------
__global__ __launch_bounds__(256,2) void filter_kernel(const u16* __restrict__ sig,
                                                       const u16* __restrict__ y1pad,
                                                       const float* __restrict__ bnscale,
                                                       const float* __restrict__ bnshift,
                                                       u16* __restrict__ y2pad,
                                                       float* __restrict__ hinsum,
                                                       float* __restrict__ hinsumsq){
  __shared__ float sc[72], sh[72];
  __shared__ float ov[256][33];
  __shared__ float ps[8][32][2];
  int t = threadIdx.x;
  if (t < 72){ sc[t] = bnscale[t]; sh[t] = bnshift[t]; }
  __syncthreads();
  int n = blockIdx.x >> 8, h = blockIdx.x & 255;

  float sv[72];
  const u16* sp = sig + ((size_t)(n*65536 + h*256 + t))*80;
  #pragma unroll
  for (int i = 0; i < 9; ++i){
    uint4 v = *(const uint4*)(sp + i*8);
    const u16* e = (const u16*)&v;
    #pragma unroll
    for (int j = 0; j < 8; ++j) sv[i*8+j] = b2f(e[j]);
  }
  float mx = -1e30f;
  #pragma unroll
  for (int c = 0; c < 72; ++c){ sv[c] = sv[c]*sc[c] + sh[c]; mx = fmaxf(mx, sv[c]); }
  float sum = 0.f;
  #pragma unroll
  for (int c = 0; c < 72; ++c){ sv[c] = __expf(sv[c] - mx); sum += sv[c]; }
  float inv = -1.f/sum;
  #pragma unroll
  for (int c = 0; c < 72; ++c) sv[c] *= inv;          // sv = -softmax
  #pragma unroll
  for (int g = 0; g < 8; ++g) sv[g*9+4] += 1.f;       // kern = delta - softmax

  // reflect row/col source coordinates (padded y1pad layout, interior-only valid)
  int srow[3], scol[3];
  #pragma unroll
  for (int i = 0; i < 3; ++i){
    int ir = h + i - 1; srow[i] = ((ir < 0) ? 1 : (ir > 255 ? 254 : ir)) + 1;
    int ic = t + i - 1; scol[i] = ((ic < 0) ? 1 : (ic > 255 ? 254 : ic)) + 1;
  }

  #pragma unroll
  for (int g = 0; g < 8; ++g){
    float o[8] = {0,0,0,0,0,0,0,0};
    #pragma unroll
    for (int i = 0; i < 3; ++i)
      #pragma unroll
      for (int j = 0; j < 3; ++j){
        uint4 v = *(const uint4*)(y1pad + ((size_t)(n*PD + srow[i])*PD + scol[j])*CIN + g*8);
        const u16* e = (const u16*)&v;
        float k = sv[g*9 + i*3 + j];
        #pragma unroll
        for (int jj = 0; jj < 8; ++jj) o[jj] = fmaf(k, b2f(e[jj]), o[jj]);
      }
    u16 ob[8];
    #pragma unroll
    for (int jj = 0; jj < 8; ++jj) ob[jj] = f2b(o[jj]);
    *(uint4*)(y2pad + ((size_t)(n*PD + h + 1)*PD + (t + 1))*CIN + g*8) = *(uint4*)ob;
    if (g < 4){
      #pragma unroll
      for (int jj = 0; jj < 8; ++jj) ov[t][g*8 + jj] = o[jj];
    }
  }

  // HIN partial stats: transpose-reduce over LDS
  __syncthreads();
  {
    int c = t & 31, seg = t >> 5;
    float s = 0.f, q = 0.f;
    #pragma unroll
    for (int rr = 0; rr < 32; ++rr){
      float v = ov[seg*32 + rr][c];
      s += v; q += v*v;
    }
    ps[seg][c][0] = s; ps[seg][c][1] = q;
  }
  __syncthreads();
  if (t < 64){
    int c = t >> 1, which = t & 1;
    float v = 0.f;
    #pragma unroll
    for (int seg = 0; seg < 8; ++seg) v += ps[seg][c][which];
    atomicAdd(which ? &hinsumsq[n*32 + c] : &hinsum[n*32 + c], v);
  }
}

__global__ void hinfinal_kernel(const float* __restrict__ hinsum, const float* __restrict__ hinsumsq,
                                float* __restrict__ hmu, float* __restrict__ hrs){
  int i = threadIdx.x;
  if (i < 128){
    const float M = 65536.f;
    float mu  = hinsum[i] / M;
    float var = hinsumsq[i] / M - mu*mu;
    hmu[i] = mu;
    hrs[i] = rsqrtf(var + EPSV);
  }
}

// ---------- launch ----------
extern "C" void kernel_launch(void* const* d_in, const int* in_sizes, int n_in,
                              void* d_out, int out_size, void* d_ws, size_t ws_size,
                              hipStream_t stream){
  const float* x     = (const float*)d_in[0];
  const float* w1    = (const float*)d_in[1];
  const float* b1    = (const float*)d_in[2];
  const float* wf    = (const float*)d_in[3];
  const float* gamma = (const float*)d_in[4];
  const float* beta  = (const float*)d_in[5];
  const float* w2    = (const float*)d_in[6];
  const float* b2    = (const float*)d_in[7];
  const float* wr    = (const float*)d_in[8];
  const float* br    = (const float*)d_in[9];

  char* ws = (char*)d_ws;
  const size_t PADB = (size_t)NN*PD*PD*CIN*2;   // 34,080,768 bytes
  u16* xpad  = (u16*)(ws);
  u16* y1pad = (u16*)(ws + PADB);
  u16* y2pad = (u16*)(ws + 2*PADB);
  float* stats = (float*)(ws + 3*PADB);
  float* bnsum   = stats;        float* bnsumsq = stats + 80;
  float* bnscale = stats + 160;  float* bnshift = stats + 240;
  float* hinsum  = stats + 320;  float* hinsumsq= stats + 448;
  float* hmu     = stats + 576;  float* hrs     = stats + 704;
  u16* wB1 = (u16*)(ws + 3*PADB + 4096);
  u16* wBf = wB1 + 9*64*64;
  u16* wB2 = wBf + 9*80*64;
  u16* wBr = wB2 + 9*64*64;

  u16* sig = (u16*)d_out;        // 41.9MB bf16, overwritten by conv2's f32 output later
  float* out = (float*)d_out;

  hipMemsetAsync(stats, 0, 4096, stream);
  prep_kernel<<<180, 256, 0, stream>>>(w1, wf, w2, wr, wB1, wBf, wB2, wBr);
  padx_kernel<<<NN*HH, 256, 0, stream>>>(x, xpad);
  conv_mfma<4,0><<<2048, 256, 0, stream>>>(xpad, wB1, b1, y1pad, nullptr, nullptr, nullptr, nullptr, nullptr, nullptr, nullptr, nullptr);
  conv_mfma<5,1><<<2048, 256, 0, stream>>>(y1pad, wBf, nullptr, sig, nullptr, nullptr, nullptr, nullptr, nullptr, nullptr, bnsum, bnsumsq);
  bnfinal_kernel<<<1, 80, 0, stream>>>(bnsum, bnsumsq, gamma, beta, bnscale, bnshift);
  filter_kernel<<<NN*HH, 256, 0, stream>>>(sig, y1pad, bnscale, bnshift, y2pad, hinsum, hinsumsq);
  hinfinal_kernel<<<1, 128, 0, stream>>>(hinsum, hinsumsq, hmu, hrs);
  conv_mfma<4,2><<<2048, 256, 0, stream>>>(y2pad, wB2, b2, nullptr, out, xpad, wBr, br, hmu, hrs, nullptr, nullptr);
}

// Round 4
// 548.667 us; speedup vs baseline: 3.8636x; 1.0372x over previous
//
#include <hip/hip_runtime.h>

typedef unsigned short u16;
typedef __attribute__((ext_vector_type(8))) short bf16x8;
typedef __attribute__((ext_vector_type(4))) float f32x4;

#define NN 4
#define HH 256
#define WW 256
#define PD 258
#define CIN 64
#define EPSV 1e-5f

__device__ __forceinline__ float b2f(u16 x){ union{unsigned u; float f;} q; q.u = ((unsigned)x)<<16; return q.f; }
__device__ __forceinline__ u16 f2b(float f){ union{float f; unsigned u;} q; q.f = f; unsigned r = q.u + 0x7FFF + ((q.u>>16)&1u); return (u16)(r>>16); }
__device__ __forceinline__ float leakyf(float x){ return x >= 0.f ? x : 0.01f*x; }

// ---------- prep: weights OIHW f32 -> [tap][cout][cin] bf16 ----------
__global__ void prep_kernel(const float* __restrict__ w1, const float* __restrict__ wf,
                            const float* __restrict__ w2, const float* __restrict__ wr,
                            u16* __restrict__ wB1, u16* __restrict__ wBf,
                            u16* __restrict__ wB2, u16* __restrict__ wBr){
  int idx = blockIdx.x*256 + threadIdx.x;
  if (idx < 9*64*64){
    int tap = idx/4096, r = idx%4096, cout = r/64, cin = r%64;
    int src = (cout*64 + cin)*9 + tap;
    wB1[idx] = f2b(w1[src]);
    wB2[idx] = f2b(w2[src]);
  }
  if (idx < 9*80*64){
    int tap = idx/5120, r = idx%5120, cout = r/64, cin = r%64;
    float v = (cout < 72) ? wf[(cout*64 + cin)*9 + tap] : 0.f;
    wBf[idx] = f2b(v);
  }
  if (idx < 64*64){
    int cout = idx/64, cin = idx%64;
    wBr[idx] = f2b(wr[cout*64 + cin]);
  }
}

// ---------- pad_x: x NCHW f32 -> xpad NHWC bf16 [n][258][258][64], zero borders ----------
__global__ __launch_bounds__(256) void padx_kernel(const float* __restrict__ x, u16* __restrict__ xpad){
  int n = blockIdx.x >> 8, h = blockIdx.x & 255, t = threadIdx.x;
  u16* dstrow = xpad + ((size_t)(n*PD + h + 1)*PD)*CIN;
  const uint4 z = {0,0,0,0};
  #pragma unroll
  for (int c8 = 0; c8 < 8; ++c8){
    u16 buf[8];
    #pragma unroll
    for (int j = 0; j < 8; ++j)
      buf[j] = f2b(x[((size_t)(n*64 + c8*8 + j))*65536 + h*256 + t]);
    *(uint4*)(dstrow + (size_t)(t+1)*CIN + c8*8) = *(uint4*)buf;
  }
  if (t == 0)   { for (int c8 = 0; c8 < 8; ++c8) *(uint4*)(dstrow + 0*CIN   + c8*8) = z; }
  if (t == 255) { for (int c8 = 0; c8 < 8; ++c8) *(uint4*)(dstrow + 257*CIN + c8*8) = z; }
  if (h == 0 || h == 255){
    u16* brow = xpad + ((size_t)(n*PD + (h == 0 ? 0 : 257))*PD)*CIN;
    for (int p = t; p < PD; p += 256)
      for (int c8 = 0; c8 < 8; ++c8) *(uint4*)(brow + (size_t)p*CIN + c8*8) = z;
  }
}

// ---------- reflect borders of y1pad ----------
__global__ void reflect_kernel(u16* __restrict__ y1pad){
  int idx = blockIdx.x*256 + threadIdx.x;
  if (idx >= 4*1028*8) return;
  int n = idx/(1028*8), rem = idx%(1028*8), p = rem >> 3, cc = rem & 7;
  int pr, pc;
  if      (p < 258)  { pr = 0;   pc = p; }
  else if (p < 516)  { pr = 257; pc = p - 258; }
  else if (p < 772)  { pr = 1 + (p - 516); pc = 0; }
  else               { pr = 1 + (p - 772); pc = 257; }
  int sr = (pr == 0) ? 2 : ((pr == 257) ? 255 : pr);
  int sc = (pc == 0) ? 2 : ((pc == 257) ? 255 : pc);
  uint4 v = *(const uint4*)(y1pad + ((size_t)(n*PD + sr)*PD + sc)*CIN + cc*8);
  *(uint4*)(y1pad + ((size_t)(n*PD + pr)*PD + pc)*CIN + cc*8) = v;
}

// ---------- MFMA conv core (no A staging: direct global per-tap fragment loads) ----------
// MODE 0: conv1 (A=xpad zero-padded, +bias, out=y1pad interior bf16)
// MODE 1: convF (A=y1pad incl. reflect ring, out=sig [n][hw][80] bf16, + BN sum/sumsq atomics)
// MODE 2: conv2 (A=y2pad pre-transformed+zero ring, epilogue leaky(+b2) + 1x1(xpad,wBr) + br -> f32 NCHW)
template<int NF, int MODE>
__global__ __launch_bounds__(256, (NF == 5) ? 3 : 4) void conv_mfma(
    const u16* __restrict__ Ain, const u16* __restrict__ wB, const float* __restrict__ bias,
    u16* __restrict__ outB, float* __restrict__ outF,
    const u16* __restrict__ xpad, const u16* __restrict__ wBr,
    const float* __restrict__ br,
    float* __restrict__ bnsum, float* __restrict__ bnsumsq){

  constexpr int NC = NF*16;
  __shared__ __align__(16) u16 Bx[(MODE < 2) ? 128*NC : 8];
  __shared__ float bnpart[(MODE == 1) ? 4 : 1][NF][16][2];

  int t = threadIdx.x, lane = t & 63, wv = t >> 6;
  int bid = blockIdx.x;
  int n = bid >> 9, r = bid & 511, h = r >> 1, wt = r & 1, w0 = wt*128;
  int l15 = lane & 15, l4 = lane >> 4;

  const u16* An = Ain + (size_t)n*PD*PD*CIN;
  const int pc0 = w0 + wv*32 + l15;      // + mf*16 + dw gives padded col

  f32x4 acc[2][NF];
  #pragma unroll
  for (int mf = 0; mf < 2; ++mf)
    #pragma unroll
    for (int f = 0; f < NF; ++f) acc[mf][f] = (f32x4){0.f,0.f,0.f,0.f};

  #pragma unroll
  for (int tap = 0; tap < 9; ++tap){
    const int dh = tap/3, dw = tap%3;
    bf16x8 bf[2][NF];
    #pragma unroll
    for (int ks = 0; ks < 2; ++ks)
      #pragma unroll
      for (int f = 0; f < NF; ++f)
        bf[ks][f] = *(const bf16x8*)(wB + ((size_t)(tap*NC + f*16 + l15))*64 + ks*32 + l4*8);
    const u16* rowp = An + ((size_t)(h + dh)*PD)*CIN;
    #pragma unroll
    for (int mf = 0; mf < 2; ++mf){
      #pragma unroll
      for (int ks = 0; ks < 2; ++ks){
        bf16x8 af = *(const bf16x8*)(rowp + (size_t)(pc0 + mf*16 + dw)*CIN + (ks*4 + l4)*8);
        #pragma unroll
        for (int f = 0; f < NF; ++f)
          acc[mf][f] = __builtin_amdgcn_mfma_f32_16x16x32_bf16(af, bf[ks][f], acc[mf][f], 0, 0, 0);
      }
    }
  }

  if (MODE < 2){
    // BN partial stats (MODE 1)
    if (MODE == 1){
      #pragma unroll
      for (int f = 0; f < NF; ++f){
        float s = 0.f, q = 0.f;
        #pragma unroll
        for (int mf = 0; mf < 2; ++mf)
          #pragma unroll
          for (int reg = 0; reg < 4; ++reg){ float v = acc[mf][f][reg]; s += v; q += v*v; }
        s += __shfl_xor(s, 16); q += __shfl_xor(q, 16);
        s += __shfl_xor(s, 32); q += __shfl_xor(q, 32);
        if (l4 == 0){ bnpart[wv][f][l15][0] = s; bnpart[wv][f][l15][1] = q; }
      }
    }
    // write acc -> Bx (bf16), then coalesced copy out
    #pragma unroll
    for (int mf = 0; mf < 2; ++mf)
      #pragma unroll
      for (int f = 0; f < NF; ++f){
        int cout = f*16 + l15;
        float bv = (MODE == 0) ? bias[cout] : 0.f;
        #pragma unroll
        for (int reg = 0; reg < 4; ++reg){
          int px = wv*32 + mf*16 + l4*4 + reg;
          Bx[px*NC + cout] = f2b(acc[mf][f][reg] + bv);
        }
      }
    __syncthreads();
    const int nch = NC/8;
    for (int idx = t; idx < 128*nch; idx += 256){
      int px = idx/nch, c8 = idx - px*nch;
      uint4 v = *(const uint4*)(Bx + px*NC + c8*8);
      if (MODE == 0)
        *(uint4*)(outB + ((size_t)(n*PD + h + 1)*PD + (w0 + 1 + px))*CIN + c8*8) = v;
      else
        *(uint4*)(outB + ((size_t)(n*65536 + h*256 + w0 + px))*80 + c8*8) = v;
    }
    if (MODE == 1 && t < 160){
      int c = t >> 1, which = t & 1;
      if (c < 72){
        float v = bnpart[0][c>>4][c&15][which] + bnpart[1][c>>4][c&15][which]
                + bnpart[2][c>>4][c&15][which] + bnpart[3][c>>4][c&15][which];
        atomicAdd(which ? &bnsumsq[c] : &bnsum[c], v);
      }
    }
  } else {
    // leaky(conv + b2), then residual 1x1 on xpad (direct loads), then +br, store f32 NCHW
    #pragma unroll
    for (int mf = 0; mf < 2; ++mf)
      #pragma unroll
      for (int f = 0; f < NF; ++f){
        float bv = bias[f*16 + l15];
        #pragma unroll
        for (int reg = 0; reg < 4; ++reg)
          acc[mf][f][reg] = leakyf(acc[mf][f][reg] + bv);
      }
    f32x4 racc[2][NF];
    #pragma unroll
    for (int mf = 0; mf < 2; ++mf)
      #pragma unroll
      for (int f = 0; f < NF; ++f) racc[mf][f] = (f32x4){0.f,0.f,0.f,0.f};
    bf16x8 brf[2][NF];
    #pragma unroll
    for (int ks = 0; ks < 2; ++ks)
      #pragma unroll
      for (int f = 0; f < NF; ++f)
        brf[ks][f] = *(const bf16x8*)(wBr + ((size_t)(f*16 + l15))*64 + ks*32 + l4*8);
    const u16* Xn = xpad + ((size_t)(n*PD + h + 1)*PD + 1)*CIN;
    #pragma unroll
    for (int mf = 0; mf < 2; ++mf)
      #pragma unroll
      for (int ks = 0; ks < 2; ++ks){
        bf16x8 xf = *(const bf16x8*)(Xn + (size_t)(pc0 + mf*16)*CIN + (ks*4 + l4)*8);
        #pragma unroll
        for (int f = 0; f < NF; ++f)
          racc[mf][f] = __builtin_amdgcn_mfma_f32_16x16x32_bf16(xf, brf[ks][f], racc[mf][f], 0, 0, 0);
      }
    #pragma unroll
    for (int mf = 0; mf < 2; ++mf)
      #pragma unroll
      for (int f = 0; f < NF; ++f){
        int cout = f*16 + l15;
        float bb = br[cout];
        float4 o;
        o.x = acc[mf][f][0] + racc[mf][f][0] + bb;
        o.y = acc[mf][f][1] + racc[mf][f][1] + bb;
        o.z = acc[mf][f][2] + racc[mf][f][2] + bb;
        o.w = acc[mf][f][3] + racc[mf][f][3] + bb;
        int px = wv*32 + mf*16 + l4*4;
        *(float4*)(outF + ((size_t)(n*64 + cout))*65536 + h*256 + w0 + px) = o;
      }
  }
}

__global__ void bnfinal_kernel(const float* __restrict__ bnsum, const float* __restrict__ bnsumsq,
                               const float* __restrict__ gamma, const float* __restrict__ beta,
                               float* __restrict__ bnscale, float* __restrict__ bnshift){
  int c = threadIdx.x;
  if (c < 72){
    const float M = 262144.f;
    float mu  = bnsum[c] / M;
    float var = bnsumsq[c] / M - mu*mu;
    float sc  = gamma[c] * rsqrtf(var + EPSV);
    bnscale[c] = sc;
    bnshift[c] = beta[c] - mu*sc;
  }
}

// ---------- filter: BN+softmax(72)+spatial filter -> y2pad interior; + HIN partial stats ----------
__global__ __launch_bounds__(256,2) void filter_kernel(const u16* __restrict__ sig,
                                                       const u16* __restrict__ y1pad,
                                                       const float* __restrict__ bnscale,
                                                       const float* __restrict__ bnshift,
                                                       u16* __restrict__ y2pad,
                                                       float* __restrict__ hinsum,
                                                       float* __restrict__ hinsumsq){
  __shared__ float sc[72], sh[72];
  __shared__ float ov[256][33];
  __shared__ float ps[8][32][2];
  int t = threadIdx.x;
  if (t < 72){ sc[t] = bnscale[t]; sh[t] = bnshift[t]; }
  __syncthreads();
  int n = blockIdx.x >> 8, h = blockIdx.x & 255;

  float sv[72];
  const u16* sp = sig + ((size_t)(n*65536 + h*256 + t))*80;
  #pragma unroll
  for (int i = 0; i < 9; ++i){
    uint4 v = *(const uint4*)(sp + i*8);
    const u16* e = (const u16*)&v;
    #pragma unroll
    for (int j = 0; j < 8; ++j) sv[i*8+j] = b2f(e[j]);
  }
  float mx = -1e30f;
  #pragma unroll
  for (int c = 0; c < 72; ++c){ sv[c] = sv[c]*sc[c] + sh[c]; mx = fmaxf(mx, sv[c]); }
  float sum = 0.f;
  #pragma unroll
  for (int c = 0; c < 72; ++c){ sv[c] = __expf(sv[c] - mx); sum += sv[c]; }
  float inv = -1.f/sum;
  #pragma unroll
  for (int c = 0; c < 72; ++c) sv[c] *= inv;          // sv = -softmax
  #pragma unroll
  for (int g = 0; g < 8; ++g) sv[g*9+4] += 1.f;       // kern = delta - softmax

  int srow[3], scol[3];
  #pragma unroll
  for (int i = 0; i < 3; ++i){
    int ir = h + i - 1; srow[i] = ((ir < 0) ? 1 : (ir > 255 ? 254 : ir)) + 1;
    int ic = t + i - 1; scol[i] = ((ic < 0) ? 1 : (ic > 255 ? 254 : ic)) + 1;
  }

  #pragma unroll
  for (int g = 0; g < 8; ++g){
    float o[8] = {0,0,0,0,0,0,0,0};
    #pragma unroll
    for (int i = 0; i < 3; ++i)
      #pragma unroll
      for (int j = 0; j < 3; ++j){
        uint4 v = *(const uint4*)(y1pad + ((size_t)(n*PD + srow[i])*PD + scol[j])*CIN + g*8);
        const u16* e = (const u16*)&v;
        float k = sv[g*9 + i*3 + j];
        #pragma unroll
        for (int jj = 0; jj < 8; ++jj) o[jj] = fmaf(k, b2f(e[jj]), o[jj]);
      }
    u16 ob[8];
    #pragma unroll
    for (int jj = 0; jj < 8; ++jj) ob[jj] = f2b(o[jj]);
    *(uint4*)(y2pad + ((size_t)(n*PD + h + 1)*PD + (t + 1))*CIN + g*8) = *(uint4*)ob;
    if (g < 4){
      #pragma unroll
      for (int jj = 0; jj < 8; ++jj) ov[t][g*8 + jj] = o[jj];
    }
  }

  __syncthreads();
  {
    int c = t & 31, seg = t >> 5;
    float s = 0.f, q = 0.f;
    #pragma unroll
    for (int rr = 0; rr < 32; ++rr){
      float v = ov[seg*32 + rr][c];
      s += v; q += v*v;
    }
    ps[seg][c][0] = s; ps[seg][c][1] = q;
  }
  __syncthreads();
  if (t < 64){
    int c = t >> 1, which = t & 1;
    float v = 0.f;
    #pragma unroll
    for (int seg = 0; seg < 8; ++seg) v += ps[seg][c][which];
    atomicAdd(which ? &hinsumsq[n*32 + c] : &hinsum[n*32 + c], v);
  }
}

__global__ void hinfinal_kernel(const float* __restrict__ hinsum, const float* __restrict__ hinsumsq,
                                float* __restrict__ hmu, float* __restrict__ hrs){
  int i = threadIdx.x;
  if (i < 128){
    const float M = 65536.f;
    float mu  = hinsum[i] / M;
    float var = hinsumsq[i] / M - mu*mu;
    hmu[i] = mu;
    hrs[i] = rsqrtf(var + EPSV);
  }
}

// ---------- HIN apply + leaky in place on y2pad; zero the pad ring ----------
__global__ __launch_bounds__(256) void hinapply_kernel(u16* __restrict__ y2pad,
                                                       const float* __restrict__ hmu,
                                                       const float* __restrict__ hrs){
  int n = blockIdx.x / PD, pr = blockIdx.x % PD, t = threadIdx.x;
  u16* row = y2pad + (size_t)(n*PD + pr)*PD*CIN;
  bool ringrow = (pr == 0) || (pr == PD-1);
  for (int idx = t; idx < PD*8; idx += 256){
    int px = idx >> 3, cc = idx & 7;
    uint4* p = (uint4*)(row + (size_t)px*CIN + cc*8);
    if (ringrow || px == 0 || px == PD-1){
      uint4 z = {0,0,0,0}; *p = z; continue;
    }
    uint4 v = *p;
    u16* e = (u16*)&v;
    if (cc < 4){
      int cb = n*32 + cc*8;
      #pragma unroll
      for (int j = 0; j < 8; ++j){
        float f = (b2f(e[j]) - hmu[cb+j]) * hrs[cb+j];
        e[j] = f2b(leakyf(f));
      }
    } else {
      #pragma unroll
      for (int j = 0; j < 8; ++j) e[j] = f2b(leakyf(b2f(e[j])));
    }
    *p = v;
  }
}

// ---------- launch ----------
extern "C" void kernel_launch(void* const* d_in, const int* in_sizes, int n_in,
                              void* d_out, int out_size, void* d_ws, size_t ws_size,
                              hipStream_t stream){
  const float* x     = (const float*)d_in[0];
  const float* w1    = (const float*)d_in[1];
  const float* b1    = (const float*)d_in[2];
  const float* wf    = (const float*)d_in[3];
  const float* gamma = (const float*)d_in[4];
  const float* beta  = (const float*)d_in[5];
  const float* w2    = (const float*)d_in[6];
  const float* b2    = (const float*)d_in[7];
  const float* wr    = (const float*)d_in[8];
  const float* br    = (const float*)d_in[9];

  char* ws = (char*)d_ws;
  const size_t PADB = (size_t)NN*PD*PD*CIN*2;   // 34,080,768 bytes
  u16* xpad  = (u16*)(ws);
  u16* y1pad = (u16*)(ws + PADB);
  u16* y2pad = (u16*)(ws + 2*PADB);
  float* stats = (float*)(ws + 3*PADB);
  float* bnsum   = stats;        float* bnsumsq = stats + 80;
  float* bnscale = stats + 160;  float* bnshift = stats + 240;
  float* hinsum  = stats + 320;  float* hinsumsq= stats + 448;
  float* hmu     = stats + 576;  float* hrs     = stats + 704;
  u16* wB1 = (u16*)(ws + 3*PADB + 4096);
  u16* wBf = wB1 + 9*64*64;
  u16* wB2 = wBf + 9*80*64;
  u16* wBr = wB2 + 9*64*64;

  u16* sig = (u16*)d_out;        // 41.9MB bf16, overwritten by conv2's f32 output later
  float* out = (float*)d_out;

  hipMemsetAsync(stats, 0, 4096, stream);
  prep_kernel<<<180, 256, 0, stream>>>(w1, wf, w2, wr, wB1, wBf, wB2, wBr);
  padx_kernel<<<NN*HH, 256, 0, stream>>>(x, xpad);
  conv_mfma<4,0><<<2048, 256, 0, stream>>>(xpad, wB1, b1, y1pad, nullptr, nullptr, nullptr, nullptr, nullptr, nullptr);
  reflect_kernel<<<(4*1028*8 + 255)/256, 256, 0, stream>>>(y1pad);
  conv_mfma<5,1><<<2048, 256, 0, stream>>>(y1pad, wBf, nullptr, sig, nullptr, nullptr, nullptr, nullptr, bnsum, bnsumsq);
  bnfinal_kernel<<<1, 80, 0, stream>>>(bnsum, bnsumsq, gamma, beta, bnscale, bnshift);
  filter_kernel<<<NN*HH, 256, 0, stream>>>(sig, y1pad, bnscale, bnshift, y2pad, hinsum, hinsumsq);
  hinfinal_kernel<<<1, 128, 0, stream>>>(hinsum, hinsumsq, hmu, hrs);
  hinapply_kernel<<<NN*PD, 256, 0, stream>>>(y2pad, hmu, hrs);
  conv_mfma<4,2><<<2048, 256, 0, stream>>>(y2pad, wB2, b2, nullptr, out, xpad, wBr, br, nullptr, nullptr);
}

// Round 5
// 466.460 us; speedup vs baseline: 4.5446x; 1.1762x over previous
//
#include <hip/hip_runtime.h>

typedef unsigned short u16;
typedef __attribute__((ext_vector_type(8))) short bf16x8;
typedef __attribute__((ext_vector_type(4))) float f32x4;

#define NN 4
#define HH 256
#define WW 256
#define PD 258
#define CIN 64
#define EPSV 1e-5f

__device__ __forceinline__ float b2f(u16 x){ union{unsigned u; float f;} q; q.u = ((unsigned)x)<<16; return q.f; }
__device__ __forceinline__ u16 f2b(float f){ union{float f; unsigned u;} q; q.f = f; unsigned r = q.u + 0x7FFF + ((q.u>>16)&1u); return (u16)(r>>16); }
__device__ __forceinline__ float leakyf(float x){ return x >= 0.f ? x : 0.01f*x; }

// ---------- prep: weights OIHW f32 -> [tap][cout][cin] bf16 ----------
__global__ void prep_kernel(const float* __restrict__ w1, const float* __restrict__ wf,
                            const float* __restrict__ w2, const float* __restrict__ wr,
                            u16* __restrict__ wB1, u16* __restrict__ wBf,
                            u16* __restrict__ wB2, u16* __restrict__ wBr){
  int idx = blockIdx.x*256 + threadIdx.x;
  if (idx < 9*64*64){
    int tap = idx/4096, r = idx%4096, cout = r/64, cin = r%64;
    int src = (cout*64 + cin)*9 + tap;
    wB1[idx] = f2b(w1[src]);
    wB2[idx] = f2b(w2[src]);
  }
  if (idx < 9*80*64){
    int tap = idx/5120, r = idx%5120, cout = r/64, cin = r%64;
    float v = (cout < 72) ? wf[(cout*64 + cin)*9 + tap] : 0.f;
    wBf[idx] = f2b(v);
  }
  if (idx < 64*64){
    int cout = idx/64, cin = idx%64;
    wBr[idx] = f2b(wr[cout*64 + cin]);
  }
}

// ---------- pad_x: x NCHW f32 -> xpad NHWC bf16 [n][258][258][64], zero borders ----------
__global__ __launch_bounds__(256) void padx_kernel(const float* __restrict__ x, u16* __restrict__ xpad){
  int n = blockIdx.x >> 8, h = blockIdx.x & 255, t = threadIdx.x;
  u16* dstrow = xpad + ((size_t)(n*PD + h + 1)*PD)*CIN;
  const uint4 z = {0,0,0,0};
  #pragma unroll
  for (int c8 = 0; c8 < 8; ++c8){
    u16 buf[8];
    #pragma unroll
    for (int j = 0; j < 8; ++j)
      buf[j] = f2b(x[((size_t)(n*64 + c8*8 + j))*65536 + h*256 + t]);
    *(uint4*)(dstrow + (size_t)(t+1)*CIN + c8*8) = *(uint4*)buf;
  }
  if (t == 0)   { for (int c8 = 0; c8 < 8; ++c8) *(uint4*)(dstrow + 0*CIN   + c8*8) = z; }
  if (t == 255) { for (int c8 = 0; c8 < 8; ++c8) *(uint4*)(dstrow + 257*CIN + c8*8) = z; }
  if (h == 0 || h == 255){
    u16* brow = xpad + ((size_t)(n*PD + (h == 0 ? 0 : 257))*PD)*CIN;
    for (int p = t; p < PD; p += 256)
      for (int c8 = 0; c8 < 8; ++c8) *(uint4*)(brow + (size_t)p*CIN + c8*8) = z;
  }
}

// ---------- reflect borders of y1pad ----------
__global__ void reflect_kernel(u16* __restrict__ y1pad){
  int idx = blockIdx.x*256 + threadIdx.x;
  if (idx >= 4*1028*8) return;
  int n = idx/(1028*8), rem = idx%(1028*8), p = rem >> 3, cc = rem & 7;
  int pr, pc;
  if      (p < 258)  { pr = 0;   pc = p; }
  else if (p < 516)  { pr = 257; pc = p - 258; }
  else if (p < 772)  { pr = 1 + (p - 516); pc = 0; }
  else               { pr = 1 + (p - 772); pc = 257; }
  int sr = (pr == 0) ? 2 : ((pr == 257) ? 255 : pr);
  int sc = (pc == 0) ? 2 : ((pc == 257) ? 255 : pc);
  uint4 v = *(const uint4*)(y1pad + ((size_t)(n*PD + sr)*PD + sc)*CIN + cc*8);
  *(uint4*)(y1pad + ((size_t)(n*PD + pr)*PD + pc)*CIN + cc*8) = v;
}

// ---------- MFMA conv core (direct global per-tap fragment loads, XCD-chunked) ----------
// MODE 0: conv1 (A=xpad zero-padded, +bias, out=y1pad interior bf16)
// MODE 1: convF (A=y1pad incl. reflect ring, out=sig [n][hw][80] bf16, + BN sum/sumsq atomics)
// MODE 2: conv2 (A=y2pad pre-transformed+zero ring, epilogue leaky(+b2) + 1x1(xpad,wBr) + br -> f32 NCHW)
template<int NF, int MODE>
__global__ __launch_bounds__(256, (NF == 5) ? 3 : 4) void conv_mfma(
    const u16* __restrict__ Ain, const u16* __restrict__ wB, const float* __restrict__ bias,
    u16* __restrict__ outB, float* __restrict__ outF,
    const u16* __restrict__ xpad, const u16* __restrict__ wBr,
    const float* __restrict__ br,
    float* __restrict__ bnsum, float* __restrict__ bnsumsq){

  constexpr int NC = NF*16;
  __shared__ __align__(16) u16 Bx[(MODE < 2) ? 128*NC : 8];
  __shared__ float bnpart[(MODE == 1) ? 4 : 1][NF][16][2];

  int t = threadIdx.x, lane = t & 63, wv = t >> 6;
  int bid = blockIdx.x;
  int sb = (bid & 7)*256 + (bid >> 3);          // XCD-chunked swizzle (bijective: 2048 = 8*256)
  int n = sb >> 9, r = sb & 511, h = r >> 1, wt = r & 1, w0 = wt*128;
  int l15 = lane & 15, l4 = lane >> 4;

  const u16* An = Ain + (size_t)n*PD*PD*CIN;
  const int pc0 = w0 + wv*32 + l15;      // + mf*16 + dw gives padded col

  f32x4 acc[2][NF];
  #pragma unroll
  for (int mf = 0; mf < 2; ++mf)
    #pragma unroll
    for (int f = 0; f < NF; ++f) acc[mf][f] = (f32x4){0.f,0.f,0.f,0.f};

  #pragma unroll
  for (int tap = 0; tap < 9; ++tap){
    const int dh = tap/3, dw = tap%3;
    bf16x8 bf[2][NF];
    #pragma unroll
    for (int ks = 0; ks < 2; ++ks)
      #pragma unroll
      for (int f = 0; f < NF; ++f)
        bf[ks][f] = *(const bf16x8*)(wB + ((size_t)(tap*NC + f*16 + l15))*64 + ks*32 + l4*8);
    const u16* rowp = An + ((size_t)(h + dh)*PD)*CIN;
    #pragma unroll
    for (int mf = 0; mf < 2; ++mf){
      #pragma unroll
      for (int ks = 0; ks < 2; ++ks){
        bf16x8 af = *(const bf16x8*)(rowp + (size_t)(pc0 + mf*16 + dw)*CIN + (ks*4 + l4)*8);
        #pragma unroll
        for (int f = 0; f < NF; ++f)
          acc[mf][f] = __builtin_amdgcn_mfma_f32_16x16x32_bf16(af, bf[ks][f], acc[mf][f], 0, 0, 0);
      }
    }
  }

  if (MODE < 2){
    if (MODE == 1){
      #pragma unroll
      for (int f = 0; f < NF; ++f){
        float s = 0.f, q = 0.f;
        #pragma unroll
        for (int mf = 0; mf < 2; ++mf)
          #pragma unroll
          for (int reg = 0; reg < 4; ++reg){ float v = acc[mf][f][reg]; s += v; q += v*v; }
        s += __shfl_xor(s, 16); q += __shfl_xor(q, 16);
        s += __shfl_xor(s, 32); q += __shfl_xor(q, 32);
        if (l4 == 0){ bnpart[wv][f][l15][0] = s; bnpart[wv][f][l15][1] = q; }
      }
    }
    #pragma unroll
    for (int mf = 0; mf < 2; ++mf)
      #pragma unroll
      for (int f = 0; f < NF; ++f){
        int cout = f*16 + l15;
        float bv = (MODE == 0) ? bias[cout] : 0.f;
        #pragma unroll
        for (int reg = 0; reg < 4; ++reg){
          int px = wv*32 + mf*16 + l4*4 + reg;
          Bx[px*NC + cout] = f2b(acc[mf][f][reg] + bv);
        }
      }
    __syncthreads();
    const int nch = NC/8;
    for (int idx = t; idx < 128*nch; idx += 256){
      int px = idx/nch, c8 = idx - px*nch;
      uint4 v = *(const uint4*)(Bx + px*NC + c8*8);
      if (MODE == 0)
        *(uint4*)(outB + ((size_t)(n*PD + h + 1)*PD + (w0 + 1 + px))*CIN + c8*8) = v;
      else
        *(uint4*)(outB + ((size_t)(n*65536 + h*256 + w0 + px))*80 + c8*8) = v;
    }
    if (MODE == 1 && t < 160){
      int c = t >> 1, which = t & 1;
      if (c < 72){
        float v = bnpart[0][c>>4][c&15][which] + bnpart[1][c>>4][c&15][which]
                + bnpart[2][c>>4][c&15][which] + bnpart[3][c>>4][c&15][which];
        atomicAdd(which ? &bnsumsq[c] : &bnsum[c], v);
      }
    }
  } else {
    #pragma unroll
    for (int mf = 0; mf < 2; ++mf)
      #pragma unroll
      for (int f = 0; f < NF; ++f){
        float bv = bias[f*16 + l15];
        #pragma unroll
        for (int reg = 0; reg < 4; ++reg)
          acc[mf][f][reg] = leakyf(acc[mf][f][reg] + bv);
      }
    f32x4 racc[2][NF];
    #pragma unroll
    for (int mf = 0; mf < 2; ++mf)
      #pragma unroll
      for (int f = 0; f < NF; ++f) racc[mf][f] = (f32x4){0.f,0.f,0.f,0.f};
    bf16x8 brf[2][NF];
    #pragma unroll
    for (int ks = 0; ks < 2; ++ks)
      #pragma unroll
      for (int f = 0; f < NF; ++f)
        brf[ks][f] = *(const bf16x8*)(wBr + ((size_t)(f*16 + l15))*64 + ks*32 + l4*8);
    const u16* Xn = xpad + ((size_t)(n*PD + h + 1)*PD + 1)*CIN;
    #pragma unroll
    for (int mf = 0; mf < 2; ++mf)
      #pragma unroll
      for (int ks = 0; ks < 2; ++ks){
        bf16x8 xf = *(const bf16x8*)(Xn + (size_t)(pc0 + mf*16)*CIN + (ks*4 + l4)*8);
        #pragma unroll
        for (int f = 0; f < NF; ++f)
          racc[mf][f] = __builtin_amdgcn_mfma_f32_16x16x32_bf16(xf, brf[ks][f], racc[mf][f], 0, 0, 0);
      }
    #pragma unroll
    for (int mf = 0; mf < 2; ++mf)
      #pragma unroll
      for (int f = 0; f < NF; ++f){
        int cout = f*16 + l15;
        float bb = br[cout];
        float4 o;
        o.x = acc[mf][f][0] + racc[mf][f][0] + bb;
        o.y = acc[mf][f][1] + racc[mf][f][1] + bb;
        o.z = acc[mf][f][2] + racc[mf][f][2] + bb;
        o.w = acc[mf][f][3] + racc[mf][f][3] + bb;
        int px = wv*32 + mf*16 + l4*4;
        *(float4*)(outF + ((size_t)(n*64 + cout))*65536 + h*256 + w0 + px) = o;
      }
  }
}

__global__ void bnfinal_kernel(const float* __restrict__ bnsum, const float* __restrict__ bnsumsq,
                               const float* __restrict__ gamma, const float* __restrict__ beta,
                               float* __restrict__ bnscale, float* __restrict__ bnshift){
  int c = threadIdx.x;
  if (c < 72){
    const float M = 262144.f;
    float mu  = bnsum[c] / M;
    float var = bnsumsq[c] / M - mu*mu;
    float sc  = gamma[c] * rsqrtf(var + EPSV);
    bnscale[c] = sc;
    bnshift[c] = beta[c] - mu*sc;
  }
}

// ---------- filter: BN+softmax(72)+spatial filter, channel-complete per thread ----------
__global__ __launch_bounds__(256,2) void filter_kernel(const u16* __restrict__ sig,
                                                       const u16* __restrict__ y1pad,
                                                       const float* __restrict__ bnscale,
                                                       const float* __restrict__ bnshift,
                                                       u16* __restrict__ y2pad,
                                                       float* __restrict__ hinsum,
                                                       float* __restrict__ hinsumsq){
  __shared__ float sc[72], sh[72];
  __shared__ float ov[256][33];
  __shared__ float ps[8][32][2];
  int t = threadIdx.x;
  if (t < 72){ sc[t] = bnscale[t]; sh[t] = bnshift[t]; }
  __syncthreads();
  int bid = blockIdx.x;
  int sb = (bid & 7)*128 + (bid >> 3);          // XCD-chunked swizzle (bijective: 1024 = 8*128)
  int n = sb >> 8, h = sb & 255;

  // ---- load sig, BN affine, softmax over 72 (all in registers) ----
  float sv[72];
  const u16* sp = sig + ((size_t)(n*65536 + h*256 + t))*80;
  #pragma unroll
  for (int i = 0; i < 9; ++i){
    uint4 v = *(const uint4*)(sp + i*8);
    const u16* e = (const u16*)&v;
    #pragma unroll
    for (int j = 0; j < 8; ++j) sv[i*8+j] = b2f(e[j]);
  }
  float mx = -1e30f;
  #pragma unroll
  for (int c = 0; c < 72; ++c){ sv[c] = sv[c]*sc[c] + sh[c]; mx = fmaxf(mx, sv[c]); }
  float sum = 0.f;
  #pragma unroll
  for (int c = 0; c < 72; ++c){ sv[c] = __expf(sv[c] - mx); sum += sv[c]; }
  float inv = -1.f/sum;
  #pragma unroll
  for (int c = 0; c < 72; ++c) sv[c] *= inv;          // sv = -softmax
  #pragma unroll
  for (int g = 0; g < 8; ++g) sv[g*9+4] += 1.f;       // kern = delta - softmax

  int srow[3], scol[3];
  #pragma unroll
  for (int i = 0; i < 3; ++i){
    int ir = h + i - 1; srow[i] = ((ir < 0) ? 1 : (ir > 255 ? 254 : ir)) + 1;
    int ic = t + i - 1; scol[i] = ((ic < 0) ? 1 : (ic > 255 ? 254 : ic)) + 1;
  }

  // ---- accumulate all 64 channels: per tap load 128B contiguous, FMA into o[64] ----
  float o[64];
  #pragma unroll
  for (int c = 0; c < 64; ++c) o[c] = 0.f;
  const u16* yn = y1pad + (size_t)n*PD*PD*CIN;
  #pragma unroll
  for (int i = 0; i < 3; ++i){
    #pragma unroll
    for (int j = 0; j < 3; ++j){
      const u16* pp = yn + ((size_t)srow[i]*PD + scol[j])*CIN;
      #pragma unroll
      for (int c8 = 0; c8 < 8; ++c8){
        uint4 v = *(const uint4*)(pp + c8*8);
        const u16* e = (const u16*)&v;
        float k = sv[(c8)*9 + i*3 + j];     // group g == c8 (8 channels per group)
        #pragma unroll
        for (int jj = 0; jj < 8; ++jj) o[c8*8 + jj] = fmaf(k, b2f(e[jj]), o[c8*8 + jj]);
      }
    }
  }

  // ---- write full 128B per pixel, coalesced ----
  u16* wp = y2pad + ((size_t)(n*PD + h + 1)*PD + (t + 1))*CIN;
  #pragma unroll
  for (int c8 = 0; c8 < 8; ++c8){
    u16 ob[8];
    #pragma unroll
    for (int jj = 0; jj < 8; ++jj) ob[jj] = f2b(o[c8*8 + jj]);
    *(uint4*)(wp + c8*8) = *(uint4*)ob;
  }

  // ---- HIN partial stats over channels 0..31 via LDS transpose ----
  #pragma unroll
  for (int c = 0; c < 32; ++c) ov[t][c] = o[c];
  __syncthreads();
  {
    int c = t & 31, seg = t >> 5;
    float s = 0.f, q = 0.f;
    #pragma unroll
    for (int rr = 0; rr < 32; ++rr){
      float v = ov[seg*32 + rr][c];
      s += v; q += v*v;
    }
    ps[seg][c][0] = s; ps[seg][c][1] = q;
  }
  __syncthreads();
  if (t < 64){
    int c = t >> 1, which = t & 1;
    float v = 0.f;
    #pragma unroll
    for (int seg = 0; seg < 8; ++seg) v += ps[seg][c][which];
    atomicAdd(which ? &hinsumsq[n*32 + c] : &hinsum[n*32 + c], v);
  }
}

__global__ void hinfinal_kernel(const float* __restrict__ hinsum, const float* __restrict__ hinsumsq,
                                float* __restrict__ hmu, float* __restrict__ hrs){
  int i = threadIdx.x;
  if (i < 128){
    const float M = 65536.f;
    float mu  = hinsum[i] / M;
    float var = hinsumsq[i] / M - mu*mu;
    hmu[i] = mu;
    hrs[i] = rsqrtf(var + EPSV);
  }
}

// ---------- HIN apply + leaky in place on y2pad; zero the pad ring ----------
__global__ __launch_bounds__(256) void hinapply_kernel(u16* __restrict__ y2pad,
                                                       const float* __restrict__ hmu,
                                                       const float* __restrict__ hrs){
  int n = blockIdx.x / PD, pr = blockIdx.x % PD, t = threadIdx.x;
  u16* row = y2pad + (size_t)(n*PD + pr)*PD*CIN;
  bool ringrow = (pr == 0) || (pr == PD-1);
  for (int idx = t; idx < PD*8; idx += 256){
    int px = idx >> 3, cc = idx & 7;
    uint4* p = (uint4*)(row + (size_t)px*CIN + cc*8);
    if (ringrow || px == 0 || px == PD-1){
      uint4 z = {0,0,0,0}; *p = z; continue;
    }
    uint4 v = *p;
    u16* e = (u16*)&v;
    if (cc < 4){
      int cb = n*32 + cc*8;
      #pragma unroll
      for (int j = 0; j < 8; ++j){
        float f = (b2f(e[j]) - hmu[cb+j]) * hrs[cb+j];
        e[j] = f2b(leakyf(f));
      }
    } else {
      #pragma unroll
      for (int j = 0; j < 8; ++j) e[j] = f2b(leakyf(b2f(e[j])));
    }
    *p = v;
  }
}

// ---------- launch ----------
extern "C" void kernel_launch(void* const* d_in, const int* in_sizes, int n_in,
                              void* d_out, int out_size, void* d_ws, size_t ws_size,
                              hipStream_t stream){
  const float* x     = (const float*)d_in[0];
  const float* w1    = (const float*)d_in[1];
  const float* b1    = (const float*)d_in[2];
  const float* wf    = (const float*)d_in[3];
  const float* gamma = (const float*)d_in[4];
  const float* beta  = (const float*)d_in[5];
  const float* w2    = (const float*)d_in[6];
  const float* b2    = (const float*)d_in[7];
  const float* wr    = (const float*)d_in[8];
  const float* br    = (const float*)d_in[9];

  char* ws = (char*)d_ws;
  const size_t PADB = (size_t)NN*PD*PD*CIN*2;   // 34,080,768 bytes
  u16* xpad  = (u16*)(ws);
  u16* y1pad = (u16*)(ws + PADB);
  u16* y2pad = (u16*)(ws + 2*PADB);
  float* stats = (float*)(ws + 3*PADB);
  float* bnsum   = stats;        float* bnsumsq = stats + 80;
  float* bnscale = stats + 160;  float* bnshift = stats + 240;
  float* hinsum  = stats + 320;  float* hinsumsq= stats + 448;
  float* hmu     = stats + 576;  float* hrs     = stats + 704;
  u16* wB1 = (u16*)(ws + 3*PADB + 4096);
  u16* wBf = wB1 + 9*64*64;
  u16* wB2 = wBf + 9*80*64;
  u16* wBr = wB2 + 9*64*64;

  u16* sig = (u16*)d_out;        // 41.9MB bf16, overwritten by conv2's f32 output later
  float* out = (float*)d_out;

  hipMemsetAsync(stats, 0, 4096, stream);
  prep_kernel<<<180, 256, 0, stream>>>(w1, wf, w2, wr, wB1, wBf, wB2, wBr);
  padx_kernel<<<NN*HH, 256, 0, stream>>>(x, xpad);
  conv_mfma<4,0><<<2048, 256, 0, stream>>>(xpad, wB1, b1, y1pad, nullptr, nullptr, nullptr, nullptr, nullptr, nullptr);
  reflect_kernel<<<(4*1028*8 + 255)/256, 256, 0, stream>>>(y1pad);
  conv_mfma<5,1><<<2048, 256, 0, stream>>>(y1pad, wBf, nullptr, sig, nullptr, nullptr, nullptr, nullptr, bnsum, bnsumsq);
  bnfinal_kernel<<<1, 80, 0, stream>>>(bnsum, bnsumsq, gamma, beta, bnscale, bnshift);
  filter_kernel<<<NN*HH, 256, 0, stream>>>(sig, y1pad, bnscale, bnshift, y2pad, hinsum, hinsumsq);
  hinfinal_kernel<<<1, 128, 0, stream>>>(hinsum, hinsumsq, hmu, hrs);
  hinapply_kernel<<<NN*PD, 256, 0, stream>>>(y2pad, hmu, hrs);
  conv_mfma<4,2><<<2048, 256, 0, stream>>>(y2pad, wB2, b2, nullptr, out, xpad, wBr, br, nullptr, nullptr);
}